// Round 6
// baseline (141.005 us; speedup 1.0000x reference)
//
#include <hip/hip_runtime.h>
#include <stdint.h>

// Problem constants (match reference)
#define N_PRIORS 2097152
#define KTOP 512
#define NBINS 2048
#define K1BLK 2048               // k1 grid (256 threads, 1024 elems each)
#define NSEG 64                  // candidate segments (k1 block b -> seg b>>5)
#define SEGCAP 64                // slots per segment (mean 12.5, 14-sigma safe)
#define SELCAP 2048
#define SSTASH 0.9915f           // pre-filter; expected ~800 candidates
#define NSUPB 16                 // suppression blocks (each owns 32 rows)

// ws layout (first 512 B zeroed by hipMemsetAsync before k1):
// +0      u32 seg_cnt[64]       (256 B)  per-segment candidate counts
// +256    u32 done_g            (4 B)    k2 arrival counter
// +512    u64 keys_seg[4096]    (32 KB)  keys, segment-major (k1-written)
// +33280  float4 box_seg[4096]  (64 KB)  decoded pixel boxes (k1-written)
// +98816  u32 rowany_g[16]      (64 B)
// +98944  u64 supW_g[512*8]     (32 KB)  suppression matrix
//
// k1: wave-aggregated segment atomics (64 cachelines, no hotspot), decodes
// boxes in-place. k2 phase 1: atomic-free deterministic compaction from a
// 32 KB contiguous array (R4's proven-fast read path, none of the sparse
// 1.5 MB stash scatter that correlated with 36-47 us k2 times in R2/R3/R5).

__device__ __forceinline__ uint64_t pack_key(float s, int idx) {
    // descending score, ascending index tie-break (== stable top_k)
    return ((uint64_t)__float_as_uint(s) << 32) | (uint32_t)(~idx);
}

__device__ __forceinline__ float score_of(float c0, float c1) {
    #pragma clang fp contract(off)
    float m  = fmaxf(c0, c1);
    float e0 = expf(c0 - m);
    float e1 = expf(c1 - m);
    return e1 / (e0 + e1);
}

__device__ __forceinline__ int bin_of(float s) {
    #pragma clang fp contract(off)
    int b = (int)((s - 0.9f) * 20480.0f);   // 2048 bins over (0.9, 1.0]
    return b > (NBINS - 1) ? (NBINS - 1) : b;
}

__device__ __forceinline__ uint64_t shfl_xor64(uint64_t x, int mask) {
    int lo = __shfl_xor((int)(uint32_t)x, mask, 64);
    int hi = __shfl_xor((int)(uint32_t)(x >> 32), mask, 64);
    return ((uint64_t)(uint32_t)hi << 32) | (uint32_t)lo;
}

// Box decode with the EXACT reference op order (fp contract off everywhere).
__device__ __forceinline__ float4 decode_box(int idx,
                                             const float4* __restrict__ loc,
                                             const float4* __restrict__ priors) {
    #pragma clang fp contract(off)
    float4 l = loc[idx];
    float4 p = priors[idx];
    float cx = p.x + (l.x * 0.1f) * p.z;
    float cy = p.y + (l.y * 0.1f) * p.w;
    float w  = p.z * expf(l.z * 0.2f);
    float h  = p.w * expf(l.w * 0.2f);
    float x1 = cx - w * 0.5f;
    float y1 = cy - h * 0.5f;
    float x2 = x1 + w;
    float y2 = y1 + h;
    x1 *= 2048.0f; y1 *= 2048.0f; x2 *= 2048.0f; y2 *= 2048.0f;
    return make_float4(x1, y1, x2, y2);
}

// K1: stream conf once (full grid); candidates (s > SSTASH) go to segment
// blockIdx.x>>5 via wave-aggregated atomicAdd (address is block-uniform ->
// one RMW per wave; ~800 total over 64 cachelines). Box decoded here.
__global__ void k1_emit(const float4* __restrict__ conf4,
                        const float4* __restrict__ loc,
                        const float4* __restrict__ priors,
                        uint32_t* __restrict__ seg_cnt,
                        uint64_t* __restrict__ keys_seg,
                        float4* __restrict__ box_seg) {
    #pragma clang fp contract(off)
    int t = threadIdx.x;            // 256 threads
    int blk = blockIdx.x;           // 2048 blocks, 512 float4 (1024 elems) each
    int g = blk >> 5;               // segment (block-uniform)
    #pragma unroll
    for (int i = 0; i < 2; ++i) {
        int f4i = blk * 512 + t + 256 * i;
        float4 c = conf4[f4i];
        float s0 = score_of(c.x, c.y);
        float s1 = score_of(c.z, c.w);
        if (s0 > SSTASH) {
            uint32_t p = atomicAdd(&seg_cnt[g], 1u);
            if (p < SEGCAP) {
                keys_seg[g * SEGCAP + p] = pack_key(s0, f4i * 2);
                box_seg[g * SEGCAP + p]  = decode_box(f4i * 2, loc, priors);
            }
        }
        if (s1 > SSTASH) {
            uint32_t p = atomicAdd(&seg_cnt[g], 1u);
            if (p < SEGCAP) {
                keys_seg[g * SEGCAP + p] = pack_key(s1, f4i * 2 + 1);
                box_seg[g * SEGCAP + p]  = decode_box(f4i * 2 + 1, loc, priors);
            }
        }
    }
}

// K2 (fused): 16 blocks x 1024 threads.
// Phase 1 (all blocks, redundant, deterministic -- no atomics: offsets come
//   from a prefix-sum of seg_cnt, identical in every block): compact keys
//   from the 32 KB segment array -> (exact fallback if needed) ->
//   slot-carrying hybrid bitonic sort -> top-512 boxes from box_seg.
// Phase 2: block b computes suppression rows [b*32, b*32+32) -> supW_g.
// Phase 3: last-arriving block stages supW_g (agent-scope atomic loads),
//   greedy bitmask scan + epilogue.
__launch_bounds__(1024)
__global__ void k2_fused(const float4* __restrict__ loc,
                         const float4* __restrict__ priors,
                         const float4* __restrict__ conf4,
                         const uint32_t* __restrict__ seg_cnt,
                         const uint64_t* __restrict__ keys_seg,
                         const float4* __restrict__ box_seg,
                         uint32_t* done_g,
                         uint32_t* rowany_g,
                         uint64_t* supW_g,
                         float* __restrict__ out) {
    #pragma clang fp contract(off)
    __shared__ uint64_t arena[4096];        // 32 KB: sel+slt (sort) then supW stage
    uint64_t* sel  = arena;                 // [0..2048) u64 keys
    uint32_t* slt  = (uint32_t*)(arena + 2048);  // [0..2048) u32 source slots
    uint64_t* supW = arena;                 // tail phase only (sort dead)
    __shared__ uint32_t hist[NBINS];        // 8 KB (fallback only)
    __shared__ float4 bpk[KTOP];            // 8 KB pixel boxes
    __shared__ float  sar[KTOP], ssc[KTOP]; // 4 KB
    __shared__ uint64_t keepw0[8];          // valid bits (pre-NMS)
    __shared__ uint64_t keepw[8];           // final keep bits
    __shared__ uint32_t rowanyL[16];
    __shared__ uint32_t scnt[NSEG];         // staged counts
    __shared__ uint32_t segoff[NSEG];       // exclusive prefix offsets
    __shared__ uint32_t nselS, fbS, anyS, tailS;
    __shared__ int bmaxS;

    int tid = threadIdx.x;          // 1024 threads
    int lane = tid & 63, wv = tid >> 6;

    if (tid == 0) { nselS = 0u; fbS = 0u; anyS = 0u; bmaxS = 0; }
    if (tid < NSEG) scnt[tid] = seg_cnt[tid];
    __syncthreads();

    // ---- offsets: serial prefix over 64 counts (deterministic, no atomics) ----
    if (tid == 0) {
        uint32_t acc = 0u, ov = 0u;
        for (int g = 0; g < NSEG; ++g) {
            segoff[g] = acc;
            uint32_t c = scnt[g];
            if (c > SEGCAP) { ov = 1u; c = SEGCAP; }
            acc += c;
        }
        nselS = acc; fbS = ov;
    }
    __syncthreads();
    uint32_t n = nselS;
    bool fb = (fbS != 0u) || (n < KTOP) || (n > SELCAP);
    __syncthreads();

    if (!fb) {
        // ---- coalesced segmented compaction: 4096 slots / 1024 threads ----
        for (int t = tid; t < NSEG * SEGCAP; t += 1024) {
            int g = t >> 6, s = t & (SEGCAP - 1);
            if ((uint32_t)s < scnt[g]) {
                uint32_t p = segoff[g] + (uint32_t)s;
                sel[p] = keys_seg[t];
                slt[p] = (uint32_t)t;       // source slot for box fetch
            }
        }
    } else {
        // ---- exact fallback: 2-pass histogram select over all of conf ----
        if (tid == 0) nselS = 0u;
        for (int b = tid; b < NBINS; b += 1024) hist[b] = 0u;
        __syncthreads();
        for (int f = tid; f < N_PRIORS / 2; f += 1024) {
            float4 c = conf4[f];
            float s0 = score_of(c.x, c.y);
            float s1 = score_of(c.z, c.w);
            if (s0 > 0.9f) atomicAdd(&hist[bin_of(s0)], 1u);
            if (s1 > 0.9f) atomicAdd(&hist[bin_of(s1)], 1u);
        }
        __syncthreads();
        for (int off = 1; off < NBINS; off <<= 1) {
            int b0 = tid, b1 = tid + 1024;
            uint32_t v0 = hist[b0] + ((b0 + off < NBINS) ? hist[b0 + off] : 0u);
            uint32_t v1 = hist[b1] + ((b1 + off < NBINS) ? hist[b1 + off] : 0u);
            __syncthreads();
            hist[b0] = v0; hist[b1] = v1;
            __syncthreads();
        }
        if (hist[tid] >= KTOP) atomicMax(&bmaxS, tid);
        if (hist[tid + 1024] >= KTOP) atomicMax(&bmaxS, tid + 1024);
        __syncthreads();
        int B = bmaxS;
        for (int f = tid; f < N_PRIORS / 2; f += 1024) {
            float4 c = conf4[f];
            float s0 = score_of(c.x, c.y);
            float s1 = score_of(c.z, c.w);
            if (s0 > 0.9f && bin_of(s0) >= B) {
                uint32_t p = atomicAdd(&nselS, 1u);
                if (p < SELCAP) { sel[p] = pack_key(s0, 2 * f); slt[p] = p; }
            }
            if (s1 > 0.9f && bin_of(s1) >= B) {
                uint32_t p = atomicAdd(&nselS, 1u);
                if (p < SELCAP) { sel[p] = pack_key(s1, 2 * f + 1); slt[p] = p; }
            }
        }
        __syncthreads();
        n = nselS; if (n > SELCAP) n = SELCAP;
        __syncthreads();
    }
    __syncthreads();

    int P = KTOP; while (P < (int)n) P <<= 1;
    for (int t = tid; t < P; t += 1024)
        if (t >= (int)n) { sel[t] = 0ull; slt[t] = 0u; }
    __syncthreads();

    uint64_t v;       // thread tid's key  (valid for tid < min(P,1024))
    uint32_t sl;      // thread tid's slot (pairs with v through the sort)

    if (P <= 1024) {
        // ---- hybrid bitonic sort, descending (0-padding sinks) ----
        v  = (tid < P) ? sel[tid] : 0ull;
        sl = (tid < P) ? slt[tid] : 0u;
        for (int k = 2; k <= P; k <<= 1) {
            // cross-wave phases (stride >= 64): via LDS, 2 barriers each
            for (int j = k >> 1; j >= 64; j >>= 1) {
                if (tid < P) { sel[tid] = v; slt[tid] = sl; }
                __syncthreads();
                if (tid < P) {
                    uint64_t pv = sel[tid ^ j];
                    uint32_t ps = slt[tid ^ j];
                    bool wmax = (((tid & j) == 0) == ((tid & k) == 0));
                    bool take = wmax ? (pv > v) : (pv < v);
                    if (take) { v = pv; sl = ps; }
                }
                __syncthreads();
            }
            // intra-wave phases (stride <= 32): register shuffles, no barriers
            int j0 = (k >> 1) < 32 ? (k >> 1) : 32;
            for (int j = j0; j >= 1; j >>= 1) {
                uint64_t pv = shfl_xor64(v, j);
                uint32_t ps = (uint32_t)__shfl_xor((int)sl, j, 64);
                bool wmax = (((tid & j) == 0) == ((tid & k) == 0));
                bool take = wmax ? (pv > v) : (pv < v);
                v = take ? pv : v; sl = take ? ps : sl;
            }
        }
    } else {
        // ---- rare overflow path (n > 1024): LDS bitonic, paired swap ----
        for (int k = 2; k <= P; k <<= 1) {
            for (int j = k >> 1; j > 0; j >>= 1) {
                for (int t = tid; t < P; t += 1024) {
                    int ixj = t ^ j;
                    if (ixj > t) {
                        uint64_t a = sel[t], b = sel[ixj];
                        bool sw = ((t & k) == 0) ? (a < b) : (a > b);
                        if (sw) {
                            sel[t] = b; sel[ixj] = a;
                            uint32_t sa = slt[t]; slt[t] = slt[ixj]; slt[ixj] = sa;
                        }
                    }
                }
                __syncthreads();
            }
        }
        v  = (tid < KTOP) ? sel[tid] : 0ull;
        sl = (tid < KTOP) ? slt[tid] : 0u;
    }

    // ---- top-512 boxes into LDS; valid-bit ballot ----
    {
        uint64_t key = (tid < KTOP) ? v : 0ull;
        if (tid < KTOP) {
            float4 bb; float area, sc;
            if (key != 0ull) {
                sc = __uint_as_float((uint32_t)(key >> 32));
                if (!fb) {
                    bb = box_seg[sl];   // k1-decoded, bit-exact, warm 64 KB
                } else {
                    int idx = (int)(~(uint32_t)key);
                    bb = decode_box(idx, loc, priors);
                }
                area = (bb.z - bb.x + 1.0f) * (bb.w - bb.y + 1.0f);
            } else {
                bb = make_float4(0.f, 0.f, 0.f, 0.f); area = 1.f; sc = 0.f;
            }
            bpk[tid] = bb; sar[tid] = area; ssc[tid] = sc;
        }
        uint64_t vb = __ballot(key != 0ull);    // wave w covers cols 64w..64w+63
        if (lane == 0 && wv < 8) keepw0[wv] = vb;
    }
    __syncthreads();    // bpk/sar/ssc/keepw0 ready; sel/slt dead

    // ---- suppression rows for this block: 16 waves x 2 rows ----
    {
        float4 cb0 = bpk[lane +   0], cb1 = bpk[lane +  64];
        float4 cb2 = bpk[lane + 128], cb3 = bpk[lane + 192];
        float4 cb4 = bpk[lane + 256], cb5 = bpk[lane + 320];
        float4 cb6 = bpk[lane + 384], cb7 = bpk[lane + 448];
        // identical formula+inputs as decode -> bit-identical areas
        float ca0 = (cb0.z - cb0.x + 1.0f) * (cb0.w - cb0.y + 1.0f);
        float ca1 = (cb1.z - cb1.x + 1.0f) * (cb1.w - cb1.y + 1.0f);
        float ca2 = (cb2.z - cb2.x + 1.0f) * (cb2.w - cb2.y + 1.0f);
        float ca3 = (cb3.z - cb3.x + 1.0f) * (cb3.w - cb3.y + 1.0f);
        float ca4 = (cb4.z - cb4.x + 1.0f) * (cb4.w - cb4.y + 1.0f);
        float ca5 = (cb5.z - cb5.x + 1.0f) * (cb5.w - cb5.y + 1.0f);
        float ca6 = (cb6.z - cb6.x + 1.0f) * (cb6.w - cb6.y + 1.0f);
        float ca7 = (cb7.z - cb7.x + 1.0f) * (cb7.w - cb7.y + 1.0f);
        #define SUPC(c, CB, CA) do { \
            float xx1 = fmaxf(rb.x, CB.x); float yy1 = fmaxf(rb.y, CB.y); \
            float xx2 = fminf(rb.z, CB.z); float yy2 = fminf(rb.w, CB.w); \
            float ww = fmaxf(xx2 - xx1 + 1.0f, 0.0f); \
            float hh = fmaxf(yy2 - yy1 + 1.0f, 0.0f); \
            float inter = ww * hh; \
            float iou = inter / (ra + (CA) - inter); \
            uint64_t wrd = __ballot(iou > 0.4f && (64 * (c) + lane) > r); \
            if (lane == 0) supW_g[r * 8 + (c)] = wrd; \
            any |= wrd; } while (0)
        uint32_t mybits = 0u;
        int rbase = blockIdx.x * 32 + wv * 2;
        for (int rr = 0; rr < 2; ++rr) {
            int r = rbase + rr;
            float4 rb = bpk[r];     // wave-uniform broadcast
            float ra = sar[r];
            uint64_t any = 0ull;
            SUPC(0, cb0, ca0); SUPC(1, cb1, ca1); SUPC(2, cb2, ca2); SUPC(3, cb3, ca3);
            SUPC(4, cb4, ca4); SUPC(5, cb5, ca5); SUPC(6, cb6, ca6); SUPC(7, cb7, ca7);
            if (lane == 0 && any != 0ull) mybits |= 1u << (r & 31);
        }
        #undef SUPC
        if (lane == 0 && mybits != 0u) atomicOr(&anyS, mybits);
    }
    __syncthreads();    // all supW_g stores of this block drained

    // ---- arrival: release fence + device counter; last block is the tail ----
    if (tid == 0) {
        rowany_g[blockIdx.x] = anyS;    // rows b*32.. -> word b exactly
        __threadfence();                // order my block's global writes
        uint32_t old = atomicAdd(done_g, 1u);
        tailS = (old == (uint32_t)(NSUPB - 1)) ? 1u : 0u;
    }
    __syncthreads();
    if (tailS == 0u) return;

    // ---- tail block: stage supW/rowany coherently, greedy scan, epilogue ----
    __threadfence();    // acquire side
    for (int i = tid; i < KTOP * 8; i += 1024)
        supW[i] = __hip_atomic_load(&supW_g[i], __ATOMIC_RELAXED,
                                    __HIP_MEMORY_SCOPE_AGENT);
    if (tid < 16)
        rowanyL[tid] = __hip_atomic_load(&rowany_g[tid], __ATOMIC_RELAXED,
                                         __HIP_MEMORY_SCOPE_AGENT);
    __syncthreads();

    if (tid == 0) {
        #define RA64(c) (((uint64_t)rowanyL[2*(c)]) | (((uint64_t)rowanyL[2*(c)+1]) << 32))
        uint64_t kp0 = keepw0[0], kp1 = keepw0[1], kp2 = keepw0[2], kp3 = keepw0[3];
        uint64_t kp4 = keepw0[4], kp5 = keepw0[5], kp6 = keepw0[6], kp7 = keepw0[7];
        #define APPLYROW(i) do { const uint64_t* rp = supW + (size_t)(i) * 8; \
            kp0 &= ~rp[0]; kp1 &= ~rp[1]; kp2 &= ~rp[2]; kp3 &= ~rp[3]; \
            kp4 &= ~rp[4]; kp5 &= ~rp[5]; kp6 &= ~rp[6]; kp7 &= ~rp[7]; } while (0)
        #define CHUNK(c, KPC) do { uint64_t ra = RA64(c); uint64_t m = (KPC) & ra; \
            while (m) { int b = __builtin_ctzll(m); APPLYROW((c) * 64 + b); \
                uint64_t above = (b == 63) ? 0ull : (~0ull << (b + 1)); \
                m = (KPC) & ra & above; } } while (0)
        CHUNK(0, kp0); CHUNK(1, kp1); CHUNK(2, kp2); CHUNK(3, kp3);
        CHUNK(4, kp4); CHUNK(5, kp5); CHUNK(6, kp6); CHUNK(7, kp7);
        keepw[0] = kp0; keepw[1] = kp1; keepw[2] = kp2; keepw[3] = kp3;
        keepw[4] = kp4; keepw[5] = kp5; keepw[6] = kp6; keepw[7] = kp7;
        #undef CHUNK
        #undef APPLYROW
        #undef RA64
    }
    __syncthreads();

    // ---- epilogue: [512,5], boxes /2048 (exact pow2), zeros if suppressed ----
    if (tid < KTOP) {
        const float inv = 1.0f / 2048.0f;
        int kb = (int)((keepw[tid >> 6] >> (tid & 63)) & 1ull);
        float4 bb = bpk[tid];
        float* o = out + tid * 5;
        if (kb) {
            o[0] = bb.x * inv;
            o[1] = bb.y * inv;
            o[2] = bb.z * inv;
            o[3] = bb.w * inv;
            o[4] = ssc[tid];
        } else {
            o[0] = 0.f; o[1] = 0.f; o[2] = 0.f; o[3] = 0.f; o[4] = 0.f;
        }
    }
}

extern "C" void kernel_launch(void* const* d_in, const int* in_sizes, int n_in,
                              void* d_out, int out_size, void* d_ws, size_t ws_size,
                              hipStream_t stream) {
    const float* loc    = (const float*)d_in[0];   // [1,N,4]
    const float* conf   = (const float*)d_in[1];   // [1,N,2]
    const float* priors = (const float*)d_in[2];   // [N,4]
    float* out = (float*)d_out;                    // [512,5]

    uint8_t* ws = (uint8_t*)d_ws;
    uint32_t* seg_cnt  = (uint32_t*)ws;              // 256 B (memset 0)
    uint32_t* done_g   = (uint32_t*)(ws + 256);      // 4 B   (memset 0)
    uint64_t* keys_seg = (uint64_t*)(ws + 512);      // 32 KB
    float4*   box_seg  = (float4*)(ws + 33280);      // 64 KB (16B aligned)
    uint32_t* rowany_g = (uint32_t*)(ws + 98816);    // 64 B
    uint64_t* supW_g   = (uint64_t*)(ws + 98944);    // 32 KB

    // zero counters (tiny graph-capturable memset); everything else is fully
    // written by its producer before any consumer reads it.
    hipMemsetAsync(ws, 0, 512, stream);
    k1_emit<<<K1BLK, 256, 0, stream>>>((const float4*)conf,
                                       (const float4*)loc,
                                       (const float4*)priors,
                                       seg_cnt, keys_seg, box_seg);
    k2_fused<<<NSUPB, 1024, 0, stream>>>((const float4*)loc, (const float4*)priors,
                                         (const float4*)conf, seg_cnt,
                                         keys_seg, box_seg,
                                         done_g, rowany_g, supW_g, out);
}